// Round 6
// baseline (108.870 us; speedup 1.0000x reference)
//
#include <hip/hip_runtime.h>

// Problem constants (fixed by setup_inputs)
#define BB     4
#define HH     640
#define WW     640
#define NLB    10
#define HWSZ   (HH * WW)     // 409600
#define BLK    128           // threads per block (2 waves)
#define PRX    4             // rows per strip (both phases)

// ---- global phase decomposition: interior (mask-free) vs boundary (masked)
// interior strips: bands 1..158 x tiles 1..158 (rows/cols 4..635) -> no padding
#define NIT    158                  // interior tiles per axis
#define NISTR  (NIT * NIT)          // 24964 interior strips per batch
#define NIBPB  196                  // ceil(NISTR/BLK) interior blocks per batch
#define NISLOT (NIBPB * BLK)        // 25088 slots per batch (124 idle guards)
#define GIBLK  (BB * NIBPB)         // 784 interior blocks
// boundary strips: bands {0,159} all tiles + tiles {0,159} bands 1..158
#define NBSTR  636                  // boundary strips per batch
#define NBBPB  5                    // ceil(NBSTR/BLK) boundary blocks per batch
#define NBSLOT (NBBPB * BLK)        // 640 slots per batch
#define GALL   (GIBLK + BB * NBBPB) // 804 global partial slots

// ---- box phase
#define SLOTS  20                   // band slots per box; waves cover slot + w*SLOTS
#define XBLKS  (BB * NLB * SLOTS)   // 800 box blocks

// ---- XCD-contiguous swizzle (bijective for NWG % 8 != 0, m204 form)
// R5: measured -2.6 us. Vertically adjacent bands share 2 of 6 halo rows; the
// swizzle keeps them on the same XCD L2 instead of refetching from HBM.
#define NWG    (GALL + XBLKS)       // 1604
#define NXCD   8
#define QW     (NWG / NXCD)         // 200
#define RW     (NWG % NXCD)         // 4

// Reduce (vin, vgr) across a 128-thread block; thread 0 stores to dst[0..1].
__device__ __forceinline__ void reduce2_write(float vin, float vgr,
                                              float* __restrict__ dst) {
    #pragma unroll
    for (int off = 32; off > 0; off >>= 1) {
        vin += __shfl_down(vin, off);
        vgr += __shfl_down(vgr, off);
    }
    __shared__ float s0[2], s1[2];
    const int lane = threadIdx.x & 63;
    const int w    = threadIdx.x >> 6;
    if (lane == 0) { s0[w] = vin; s1[w] = vgr; }
    __syncthreads();
    if (threadIdx.x == 0) {
        dst[0] = s0[0] + s0[1];
        dst[1] = s1[0] + s1[1];
    }
}

// Load the 6-float window [base, base+6) with TWO unaligned vector loads
// (dwordx4 + dwordx2, both 4B-aligned -> legal on gfx9+). Replaces
// {aligned float4 + 2 scalar loads}: 2 VMEM instr instead of 3, and the
// lane-strided scalars (16 line-touches each for 4B of data) disappear.
// All loads stay mutually independent -> full MLP (R4's shuffle variant
// created load->shfl->wait chains and regressed 20 us).
__device__ __forceinline__ void load6(const float* __restrict__ base,
                                      float w[6]) {
    float4 a; float2 b;
    __builtin_memcpy(&a, base, 16);       // cols c0-1 .. c0+2
    __builtin_memcpy(&b, base + 4, 8);    // cols c0+3 .. c0+4
    w[0] = a.x; w[1] = a.y; w[2] = a.z; w[3] = a.w; w[4] = b.x; w[5] = b.y;
}

// Process a 4-wide x PRX-tall strip with top-left center (c0, r0).
// Values outside [ry1,ry2) x [cx1,cx2) read as 0 (zero padding == mask).
// Only centers inside that rectangle accumulate (fmask).
// MASK=false: caller guarantees the full 6x6 footprint is in-bounds and every
//             center is live -> no clamps, no selects (97.5% of global strips).
// m-plane = w0*v + w1*t (sobel of m via linearity).
template<bool MASK>
__device__ __forceinline__ void strip4(const float* __restrict__ v,
                                       const float* __restrict__ t,
                                       const float* __restrict__ g,
                                       int c0, int r0, int ry1, int ry2,
                                       int cx1, int cx2, float w0, float w1,
                                       float& s_in, float& s_gr) {
    // A[plane][row i][col j]; col j=0 is c0-1 .. j=5 is c0+4
    float A[3][PRX + 2][6];
    const float* P[3] = { v, t, g };
    if (MASK) {
        // safe: unaligned window [c0-1, c0+5) is in-bounds for every row
        // (c0 multiple of 4; c0>=4 -> c0-1>=3; c0<=632 -> c0+4<=636<=639)
        const bool safe = (c0 >= 4) && (c0 <= WW - 8);
        const int c4 = min(max(c0, 0), WW - 4);   // aligned base (edge lanes)
        const int cl = max(c0 - 1, 0);
        const int cr = min(c0 + 4, WW - 1);
        bool okc[6];
        #pragma unroll
        for (int j = 0; j < 6; ++j) {
            const int cc = c0 - 1 + j;
            okc[j] = (cc >= cx1) && (cc < cx2);
        }
        #pragma unroll
        for (int i = 0; i < PRX + 2; ++i) {
            const int rr  = r0 - 1 + i;
            const bool rok = (rr >= ry1) && (rr < ry2);
            const int rb  = min(max(rr, 0), HH - 1) * WW;
            #pragma unroll
            for (int p = 0; p < 3; ++p) {
                float e[6];
                if (safe) {
                    load6(P[p] + rb + c0 - 1, e);
                } else {
                    // rare edge lanes (c0==0 or c0==636): clamped assembly;
                    // out-of-window positions are zeroed by okc below.
                    const float4 f = *(const float4*)(P[p] + rb + c4);
                    e[0] = P[p][rb + cl];
                    e[1] = f.x; e[2] = f.y; e[3] = f.z; e[4] = f.w;
                    e[5] = P[p][rb + cr];
                }
                #pragma unroll
                for (int j = 0; j < 6; ++j)
                    A[p][i][j] = (rok && okc[j]) ? e[j] : 0.0f;
            }
        }
        #pragma unroll
        for (int s = 0; s < PRX; ++s) {
            const int rc = r0 + s;                       // center row
            const bool rcin = (rc >= ry1) && (rc < ry2);
            #pragma unroll
            for (int c = 0; c < 4; ++c) {
                float gx[3], gy[3];
                #pragma unroll
                for (int p = 0; p < 3; ++p) {
                    gx[p] = (A[p][s][c + 2] - A[p][s][c])
                          + 2.0f * (A[p][s + 1][c + 2] - A[p][s + 1][c])
                          + (A[p][s + 2][c + 2] - A[p][s + 2][c]);
                    gy[p] = (A[p][s][c] + 2.0f * A[p][s][c + 1] + A[p][s][c + 2])
                          - (A[p][s + 2][c] + 2.0f * A[p][s + 2][c + 1] + A[p][s + 2][c + 2]);
                }
                const float sv  = fabsf(gx[0]) + fabsf(gy[0]);
                const float sg  = fabsf(gx[2]) + fabsf(gy[2]);
                const float gxm = w0 * gx[0] + w1 * gx[1];
                const float gym = w0 * gy[0] + w1 * gy[1];
                const float sm  = fabsf(gxm) + fabsf(gym);
                const float vc  = A[0][s + 1][c + 1];
                const float tc  = A[1][s + 1][c + 1];
                const float gc  = A[2][s + 1][c + 1];
                const float mc  = w0 * vc + w1 * tc;
                const float inb = (rcin && okc[c + 1]) ? 1.0f : 0.0f;
                s_gr += inb * fabsf(sg - fmaxf(sv, sm));
                s_in += inb * fabsf(gc - fmaxf(vc, mc));
            }
        }
    } else {
        // ---- fast path: 2 unaligned vector loads per row-plane, no selects
        #pragma unroll
        for (int i = 0; i < PRX + 2; ++i) {
            const int rb = (r0 - 1 + i) * WW;
            #pragma unroll
            for (int p = 0; p < 3; ++p)
                load6(P[p] + rb + c0 - 1, A[p][i]);
        }
        #pragma unroll
        for (int s = 0; s < PRX; ++s) {
            #pragma unroll
            for (int c = 0; c < 4; ++c) {
                float gx[3], gy[3];
                #pragma unroll
                for (int p = 0; p < 3; ++p) {
                    gx[p] = (A[p][s][c + 2] - A[p][s][c])
                          + 2.0f * (A[p][s + 1][c + 2] - A[p][s + 1][c])
                          + (A[p][s + 2][c + 2] - A[p][s + 2][c]);
                    gy[p] = (A[p][s][c] + 2.0f * A[p][s][c + 1] + A[p][s][c + 2])
                          - (A[p][s + 2][c] + 2.0f * A[p][s + 2][c + 1] + A[p][s + 2][c + 2]);
                }
                const float sv  = fabsf(gx[0]) + fabsf(gy[0]);
                const float sg  = fabsf(gx[2]) + fabsf(gy[2]);
                const float gxm = w0 * gx[0] + w1 * gx[1];
                const float gym = w0 * gy[0] + w1 * gy[1];
                const float sm  = fabsf(gxm) + fabsf(gym);
                const float vc  = A[0][s + 1][c + 1];
                const float tc  = A[1][s + 1][c + 1];
                const float gc  = A[2][s + 1][c + 1];
                const float mc  = w0 * vc + w1 * tc;
                s_gr += fabsf(sg - fmaxf(sv, sm));
                s_in += fabsf(gc - fmaxf(vc, mc));
            }
        }
    }
}

// ---------------- Fused main kernel ----------------
// logical blocks [0, GIBLK):          global interior strips (fast path)
// logical blocks [GIBLK, GALL):       global boundary strips (masked path)
// logical blocks [GALL, GALL+XBLKS):  box bands (masked path)
// Every block writes its 2 partial sums to a dedicated slot (no init needed).
__global__ __launch_bounds__(BLK) void kmain(const float* __restrict__ vis,
                                             const float* __restrict__ th,
                                             const float* __restrict__ gen,
                                             const int* __restrict__ label,
                                             float* __restrict__ gpart,
                                             float* __restrict__ xpart) {
    const int t = threadIdx.x;
    // XCD-contiguous logical block id (bijective; see #define block comment)
    const unsigned xcd = blockIdx.x % NXCD;
    const unsigned idx = blockIdx.x / NXCD;
    const unsigned bx  = (xcd < RW ? xcd * (QW + 1)
                                   : RW * (QW + 1) + (xcd - RW) * QW) + idx;
    float s_in = 0.0f, s_gr = 0.0f;
    if (bx < GIBLK) {
        // ---- global interior: gi -> (batch, band, xt), bands/tiles 1..158
        const int gi = bx * BLK + t;
        const int b  = gi / NISLOT;
        const int r  = gi - b * NISLOT;
        if (r < NISTR) {
            const int xt   = 1 + r % NIT;
            const int band = 1 + r / NIT;
            strip4<false>(vis + b * HWSZ, th + b * HWSZ, gen + b * HWSZ,
                          4 * xt, 4 * band, 0, HH, 0, WW, 0.5f, 0.5f,
                          s_in, s_gr);
        }
        reduce2_write(s_in, s_gr, gpart + bx * 2);
    } else if (bx < GALL) {
        // ---- global boundary: 636 strips/batch on the image frame
        const int q = (bx - GIBLK) * BLK + t;
        const int b = q / NBSLOT;
        const int r = q - b * NBSLOT;
        if (r < NBSTR) {
            int band, xt;
            if (r < 160)      { band = 0;   xt = r; }
            else if (r < 320) { band = 159; xt = r - 160; }
            else if (r < 478) { xt = 0;     band = 1 + (r - 320); }
            else              { xt = 159;   band = 1 + (r - 478); }
            strip4<true>(vis + b * HWSZ, th + b * HWSZ, gen + b * HWSZ,
                         4 * xt, 4 * band, 0, HH, 0, WW, 0.5f, 0.5f,
                         s_in, s_gr);
        }
        reduce2_write(s_in, s_gr, gpart + bx * 2);
    } else {
        // ---- box phase: block = (box, slot); wave w covers bands slot+w*SLOTS,
        //      stepping 2*SLOTS bands; 64-lane x 4-col (256-wide) column tiles.
        const int q    = bx - GALL;
        const int box  = q / SLOTS;
        const int slot = q % SLOTS;
        const int b    = box / NLB;
        const int w    = t >> 6;
        const int lane = t & 63;
        const int* lb  = label + box * 5;
        const int x1 = lb[1], y1 = lb[2], x2 = lb[3], y2 = lb[4];
        const int x1a = x1 & ~3;   // aligned start; cols < x1 are masked
        const float* v  = vis + b * HWSZ;
        const float* tp = th  + b * HWSZ;
        const float* g  = gen + b * HWSZ;
        for (int r0 = y1 + (slot + w * SLOTS) * PRX; r0 < y2;
             r0 += 2 * SLOTS * PRX)
            for (int cb = x1a; cb < x2; cb += 64 * 4) {
                const int c0 = cb + 4 * lane;
                // lanes fully right of the box contribute exactly 0 -> skip
                if (c0 < x2)
                    strip4<true>(v, tp, g, c0, r0, y1, y2, x1, x2,
                                 0.3f, 0.7f, s_in, s_gr);
            }
        reduce2_write(s_in, s_gr, xpart + q * 2);
    }
}

// ---------------- Finalize: reduce partials, compute all 7 outputs ----------
// out layout (flat, return order): loss_ss[4], loss_global[4], loss_label[4],
//                                  loss_in[4], loss_grad[4], ls[4], lin[4]
__global__ __launch_bounds__(256) void kfin(const float* __restrict__ gpart,
                                            const float* __restrict__ xpart,
                                            const int* __restrict__ label,
                                            const float* __restrict__ bptr,
                                            const float* __restrict__ cptr,
                                            float* __restrict__ out) {
    const int t = threadIdx.x;
    __shared__ float Sin[BB], Sgr[BB];
    __shared__ float Ls[BB * NLB], L1[BB * NLB];
    // global partial reduce: wave w = batch w
    //   interior blocks [w*NIBPB, (w+1)*NIBPB) + boundary [GIBLK+w*NBBPB, +NBBPB)
    {
        const int w = t >> 6, l = t & 63;
        float a = 0.0f, gr = 0.0f;
        for (int j = l; j < NIBPB; j += 64) {
            a  += gpart[(w * NIBPB + j) * 2 + 0];
            gr += gpart[(w * NIBPB + j) * 2 + 1];
        }
        if (l < NBBPB) {
            const int idx = GIBLK + w * NBBPB + l;
            a  += gpart[idx * 2 + 0];
            gr += gpart[idx * 2 + 1];
        }
        #pragma unroll
        for (int off = 32; off > 0; off >>= 1) {
            a  += __shfl_down(a, off);
            gr += __shfl_down(gr, off);
        }
        if (l == 0) { Sin[w] = a; Sgr[w] = gr; }
    }
    // per-box reduce over band slots + area/valid normalization
    if (t < BB * NLB) {
        float si = 0.0f, sg = 0.0f;
        #pragma unroll
        for (int s = 0; s < SLOTS; ++s) {
            si += xpart[(t * SLOTS + s) * 2 + 0];
            sg += xpart[(t * SLOTS + s) * 2 + 1];
        }
        const int* lb = label + t * 5;
        const int x1 = lb[1], y1 = lb[2], x2 = lb[3], y2 = lb[4];
        const bool valid = !((x1 == 0) && (y1 == 0) && (x2 == 0) && (y2 == 0));
        const float area = (float)((y2 - y1) * (x2 - x1));  // * C, C==1
        const float safe_area = fmaxf(area, 1.0f);
        const float vv = valid ? 1.0f : 0.0f;
        Ls[t] = sg / safe_area * vv;   // Lssim: gradient term
        L1[t] = si / safe_area * vv;   // L1loss: intensity term
    }
    __syncthreads();
    if (t < BB) {
        const float alpha = bptr[0];
        const float beta  = cptr[0];
        float cnt = 0.0f, sls = 0.0f, slin = 0.0f;
        for (int nl = 0; nl < NLB; nl++) {
            const float a = Ls[t * NLB + nl];
            const float l = L1[t * NLB + nl];
            if (a != 0.0f || l != 0.0f) cnt += 1.0f;
            sls  += a;
            slin += l;
        }
        const float safe_cnt = fmaxf(cnt, 1.0f);
        const float ls  = (cnt > 0.0f) ? (sls  / safe_cnt) : 0.0f;
        const float lin = (cnt > 0.0f) ? (slin / safe_cnt) : 0.0f;
        const float loss_label = (1.0f - beta) * ls + beta * lin;
        const float loss_in    = Sin[t] * (1.0f / (float)HWSZ);
        const float loss_grad  = Sgr[t] * (1.0f / (float)HWSZ);
        const float loss_global = alpha * loss_in + (1.0f - alpha) * loss_grad;
        out[0      + t] = 0.0f;          // loss_ss
        out[BB     + t] = loss_global;
        out[2 * BB + t] = loss_label;
        out[3 * BB + t] = loss_in;
        out[4 * BB + t] = loss_grad;
        out[5 * BB + t] = ls;
        out[6 * BB + t] = lin;
    }
}

extern "C" void kernel_launch(void* const* d_in, const int* in_sizes, int n_in,
                              void* d_out, int out_size, void* d_ws, size_t ws_size,
                              hipStream_t stream) {
    const float* bptr  = (const float*)d_in[0];
    const float* cptr  = (const float*)d_in[1];
    const float* vis   = (const float*)d_in[2];
    // d_in[3] = image_ir (unused by the reference)
    const float* gen   = (const float*)d_in[4];
    const int*   label = (const int*)d_in[5];
    const float* th    = (const float*)d_in[6];
    float* out = (float*)d_out;

    float* gpart = (float*)d_ws;            // GALL*2 floats
    float* xpart = gpart + GALL * 2;        // XBLKS*2 floats
    // Every slot is written unconditionally by its block — no memset needed.

    kmain<<<NWG, BLK, 0, stream>>>(vis, th, gen, label, gpart, xpart);
    kfin<<<1, 256, 0, stream>>>(gpart, xpart, label, bptr, cptr, out);
}

// Round 7
// 107.616 us; speedup vs baseline: 1.0117x; 1.0117x over previous
//
#include <hip/hip_runtime.h>

// Problem constants (fixed by setup_inputs)
#define BB     4
#define HH     640
#define WW     640
#define NLB    10
#define HWSZ   (HH * WW)     // 409600
#define BLK    128           // threads per block (2 waves)
#define PRX    4             // rows per strip (box phase)

// ---- global phase: LDS-tiled. Block = 128x16 px tile (32x4 strips of 4x4).
// Stage (16+2) rows x (128+8) cols x 3 planes with zero-padded borders ->
// compute needs NO masks anywhere, and all global loads are aligned float4.
#define TCW    128                  // tile cols
#define TRH    16                   // tile rows
#define TX     (WW / TCW)           // 5 col tiles
#define TY     (HH / TRH)           // 40 row tiles
#define GPBB   (TX * TY)            // 200 global blocks per batch
#define GBLKS  (BB * GPBB)          // 800 global blocks
#define LDSC   140                  // LDS row stride (136 used + 4 pad)
                                    // 140*4B=560B=16*35 -> every quad 16B-aligned;
                                    // row shift 12 banks -> <=4-way conflicts
#define NQ     34                   // staged quads per row (136 cols)
#define NSTG   (3 * 18 * NQ)        // 1836 float4 stage ops per block

// ---- box phase (R5 structure, R6's load6 reverted)
#define SLOTS  20                   // band slots per box; waves cover slot + w*SLOTS
#define XBLKS  (BB * NLB * SLOTS)   // 800 box blocks

// ---- XCD-contiguous swizzle (R5: measured -2.6 us). NWG=1600 -> simple form.
// Each XCD owns a contiguous 200-block chunk; global ids order ty fastest so
// vertically adjacent tiles (sharing 2 halo rows) stay on one L2.
#define NWG    (GBLKS + XBLKS)      // 1600
#define NXCD   8
#define CPX    (NWG / NXCD)         // 200

// Reduce (vin, vgr) across a 128-thread block; thread 0 stores to dst[0..1].
__device__ __forceinline__ void reduce2_write(float vin, float vgr,
                                              float* __restrict__ dst) {
    #pragma unroll
    for (int off = 32; off > 0; off >>= 1) {
        vin += __shfl_down(vin, off);
        vgr += __shfl_down(vgr, off);
    }
    __shared__ float s0[2], s1[2];
    const int lane = threadIdx.x & 63;
    const int w    = threadIdx.x >> 6;
    if (lane == 0) { s0[w] = vin; s1[w] = vgr; }
    __syncthreads();
    if (threadIdx.x == 0) {
        dst[0] = s0[0] + s0[1];
        dst[1] = s1[0] + s1[1];
    }
}

// Box-phase strip (R5's masked path verbatim; R6's unaligned load6 reverted —
// unaligned 16B loads split per-lane into 2 line-lookups and regressed 9us).
// 4-wide x PRX-tall strip, top-left center (c0, r0). Values outside
// [ry1,ry2) x [cx1,cx2) read as 0 (zero pad == mask); only centers inside
// accumulate (fmask). m-plane = w0*v + w1*t (sobel of m via linearity).
// All loads independent -> max MLP (R4: shuffle halos serialized, +20us).
__device__ __forceinline__ void strip4m(const float* __restrict__ v,
                                        const float* __restrict__ t,
                                        const float* __restrict__ g,
                                        int c0, int r0, int ry1, int ry2,
                                        int cx1, int cx2, float w0, float w1,
                                        float& s_in, float& s_gr) {
    // A[plane][row i][col j]; col j=0 is c0-1 .. j=5 is c0+4
    float A[3][PRX + 2][6];
    const float* P[3] = { v, t, g };
    const int c4 = min(max(c0, 0), WW - 4);   // aligned float4 base (safe)
    const int cl = max(c0 - 1, 0);
    const int cr = min(c0 + 4, WW - 1);
    bool okc[6];
    #pragma unroll
    for (int j = 0; j < 6; ++j) {
        const int cc = c0 - 1 + j;
        okc[j] = (cc >= cx1) && (cc < cx2);
    }
    #pragma unroll
    for (int i = 0; i < PRX + 2; ++i) {
        const int rr  = r0 - 1 + i;
        const bool rok = (rr >= ry1) && (rr < ry2);
        const int rb  = min(max(rr, 0), HH - 1) * WW;
        #pragma unroll
        for (int p = 0; p < 3; ++p) {
            const float4 f = *(const float4*)(P[p] + rb + c4);
            const float eL = P[p][rb + cl];
            const float eR = P[p][rb + cr];
            A[p][i][0] = (rok && okc[0]) ? eL  : 0.0f;
            A[p][i][1] = (rok && okc[1]) ? f.x : 0.0f;
            A[p][i][2] = (rok && okc[2]) ? f.y : 0.0f;
            A[p][i][3] = (rok && okc[3]) ? f.z : 0.0f;
            A[p][i][4] = (rok && okc[4]) ? f.w : 0.0f;
            A[p][i][5] = (rok && okc[5]) ? eR  : 0.0f;
        }
    }
    #pragma unroll
    for (int s = 0; s < PRX; ++s) {
        const int rc = r0 + s;                       // center row
        const bool rcin = (rc >= ry1) && (rc < ry2);
        #pragma unroll
        for (int c = 0; c < 4; ++c) {
            float gx[3], gy[3];
            #pragma unroll
            for (int p = 0; p < 3; ++p) {
                gx[p] = (A[p][s][c + 2] - A[p][s][c])
                      + 2.0f * (A[p][s + 1][c + 2] - A[p][s + 1][c])
                      + (A[p][s + 2][c + 2] - A[p][s + 2][c]);
                gy[p] = (A[p][s][c] + 2.0f * A[p][s][c + 1] + A[p][s][c + 2])
                      - (A[p][s + 2][c] + 2.0f * A[p][s + 2][c + 1] + A[p][s + 2][c + 2]);
            }
            const float sv  = fabsf(gx[0]) + fabsf(gy[0]);
            const float sg  = fabsf(gx[2]) + fabsf(gy[2]);
            const float gxm = w0 * gx[0] + w1 * gx[1];
            const float gym = w0 * gy[0] + w1 * gy[1];
            const float sm  = fabsf(gxm) + fabsf(gym);
            const float vc  = A[0][s + 1][c + 1];
            const float tc  = A[1][s + 1][c + 1];
            const float gc  = A[2][s + 1][c + 1];
            const float mc  = w0 * vc + w1 * tc;
            const float inb = (rcin && okc[c + 1]) ? 1.0f : 0.0f;
            s_gr += inb * fabsf(sg - fmaxf(sv, sm));
            s_in += inb * fabsf(gc - fmaxf(vc, mc));
        }
    }
}

// ---------------- Fused main kernel ----------------
// logical blocks [0, GBLKS):        LDS-tiled global phase (no masks)
// logical blocks [GBLKS, NWG):      box bands (masked path)
__global__ __launch_bounds__(BLK) void kmain(const float* __restrict__ vis,
                                             const float* __restrict__ th,
                                             const float* __restrict__ gen,
                                             const int* __restrict__ label,
                                             float* __restrict__ gpart,
                                             float* __restrict__ xpart) {
    const int t = threadIdx.x;
    // XCD-contiguous logical block id (NWG divisible by 8 -> simple bijection)
    const unsigned bx = (blockIdx.x % NXCD) * CPX + blockIdx.x / NXCD;
    float s_in = 0.0f, s_gr = 0.0f;
    if (bx < GBLKS) {
        // ---- global phase, LDS-tiled: bx -> (batch, tx, ty), ty fastest
        const int b   = bx / GPBB;
        const int r2  = bx - b * GPBB;
        const int tx  = r2 / TY;
        const int ty  = r2 - tx * TY;
        const int r_start = ty * TRH;
        const int c_start = tx * TCW;
        const float* P[3] = { vis + b * HWSZ, th + b * HWSZ, gen + b * HWSZ };

        __shared__ float lds[3][18][LDSC];
        // stage: rows r_start-1 .. r_start+16 (18), cols c_start-4 .. +131
        // (34 aligned quads); OOB rows/cols -> 0.0f (zero padding == border
        // mask, so the compute loop below needs NO masks at all).
        for (int i = t; i < NSTG; i += BLK) {
            const int p   = i / (18 * NQ);
            const int rem = i - p * (18 * NQ);
            const int row = rem / NQ;
            const int qc  = rem - row * NQ;
            const int gr  = r_start - 1 + row;
            const int gc  = c_start - 4 + qc * 4;
            float4 val = {0.0f, 0.0f, 0.0f, 0.0f};
            if (gr >= 0 && gr < HH) {
                const float* src = P[p] + gr * WW;
                if (gc >= 0 && gc + 3 < WW) {
                    val = *(const float4*)(src + gc);   // aligned (gc%4==0)
                } else {
                    float e0 = 0.f, e1 = 0.f, e2 = 0.f, e3 = 0.f;
                    if (gc + 0 >= 0 && gc + 0 < WW) e0 = src[gc + 0];
                    if (gc + 1 >= 0 && gc + 1 < WW) e1 = src[gc + 1];
                    if (gc + 2 >= 0 && gc + 2 < WW) e2 = src[gc + 2];
                    if (gc + 3 >= 0 && gc + 3 < WW) e3 = src[gc + 3];
                    val = {e0, e1, e2, e3};
                }
            }
            *(float4*)&lds[p][row][qc * 4] = val;
        }
        __syncthreads();

        // compute: thread = strip (sx,sy); window rows sy*4..sy*4+5,
        // cols sx*4+3..sx*4+8 (LDS col 4 == global c_start).
        const int sx = t & 31, sy = t >> 5;
        float A[3][6][6];
        #pragma unroll
        for (int p = 0; p < 3; ++p)
            #pragma unroll
            for (int i = 0; i < 6; ++i) {
                const float* row = &lds[p][sy * 4 + i][sx * 4];
                const float4 q0 = *(const float4*)(row);       // 16B-aligned
                const float4 q1 = *(const float4*)(row + 4);   // 16B-aligned
                A[p][i][0] = q0.w;
                A[p][i][1] = q1.x; A[p][i][2] = q1.y;
                A[p][i][3] = q1.z; A[p][i][4] = q1.w;
                A[p][i][5] = row[8];
            }
        #pragma unroll
        for (int s = 0; s < PRX; ++s) {
            #pragma unroll
            for (int c = 0; c < 4; ++c) {
                float gx[3], gy[3];
                #pragma unroll
                for (int p = 0; p < 3; ++p) {
                    gx[p] = (A[p][s][c + 2] - A[p][s][c])
                          + 2.0f * (A[p][s + 1][c + 2] - A[p][s + 1][c])
                          + (A[p][s + 2][c + 2] - A[p][s + 2][c]);
                    gy[p] = (A[p][s][c] + 2.0f * A[p][s][c + 1] + A[p][s][c + 2])
                          - (A[p][s + 2][c] + 2.0f * A[p][s + 2][c + 1] + A[p][s + 2][c + 2]);
                }
                const float sv  = fabsf(gx[0]) + fabsf(gy[0]);
                const float sg  = fabsf(gx[2]) + fabsf(gy[2]);
                const float gxm = 0.5f * gx[0] + 0.5f * gx[1];
                const float gym = 0.5f * gy[0] + 0.5f * gy[1];
                const float sm  = fabsf(gxm) + fabsf(gym);
                const float vc  = A[0][s + 1][c + 1];
                const float tc  = A[1][s + 1][c + 1];
                const float gc  = A[2][s + 1][c + 1];
                const float mc  = 0.5f * vc + 0.5f * tc;
                s_gr += fabsf(sg - fmaxf(sv, sm));
                s_in += fabsf(gc - fmaxf(vc, mc));
            }
        }
        reduce2_write(s_in, s_gr, gpart + bx * 2);
    } else {
        // ---- box phase: block = (box, slot); wave w covers bands slot+w*SLOTS,
        //      stepping 2*SLOTS bands; 64-lane x 4-col (256-wide) column tiles.
        const int q    = bx - GBLKS;
        const int box  = q / SLOTS;
        const int slot = q % SLOTS;
        const int b    = box / NLB;
        const int w    = t >> 6;
        const int lane = t & 63;
        const int* lb  = label + box * 5;
        const int x1 = lb[1], y1 = lb[2], x2 = lb[3], y2 = lb[4];
        const int x1a = x1 & ~3;   // aligned start; cols < x1 are masked
        const float* v  = vis + b * HWSZ;
        const float* tp = th  + b * HWSZ;
        const float* g  = gen + b * HWSZ;
        for (int r0 = y1 + (slot + w * SLOTS) * PRX; r0 < y2;
             r0 += 2 * SLOTS * PRX)
            for (int cb = x1a; cb < x2; cb += 64 * 4) {
                const int c0 = cb + 4 * lane;
                // lanes fully right of the box contribute exactly 0 -> skip
                if (c0 < x2)
                    strip4m(v, tp, g, c0, r0, y1, y2, x1, x2,
                            0.3f, 0.7f, s_in, s_gr);
            }
        reduce2_write(s_in, s_gr, xpart + q * 2);
    }
}

// ---------------- Finalize: reduce partials, compute all 7 outputs ----------
// out layout (flat, return order): loss_ss[4], loss_global[4], loss_label[4],
//                                  loss_in[4], loss_grad[4], ls[4], lin[4]
__global__ __launch_bounds__(256) void kfin(const float* __restrict__ gpart,
                                            const float* __restrict__ xpart,
                                            const int* __restrict__ label,
                                            const float* __restrict__ bptr,
                                            const float* __restrict__ cptr,
                                            float* __restrict__ out) {
    const int t = threadIdx.x;
    __shared__ float Sin[BB], Sgr[BB];
    __shared__ float Ls[BB * NLB], L1[BB * NLB];
    // global partial reduce: wave w = batch w (blocks [GPBB*w, GPBB*(w+1)))
    {
        const int w = t >> 6, l = t & 63;
        float a = 0.0f, gr = 0.0f;
        for (int j = l; j < GPBB; j += 64) {
            a  += gpart[(w * GPBB + j) * 2 + 0];
            gr += gpart[(w * GPBB + j) * 2 + 1];
        }
        #pragma unroll
        for (int off = 32; off > 0; off >>= 1) {
            a  += __shfl_down(a, off);
            gr += __shfl_down(gr, off);
        }
        if (l == 0) { Sin[w] = a; Sgr[w] = gr; }
    }
    // per-box reduce over band slots + area/valid normalization
    if (t < BB * NLB) {
        float si = 0.0f, sg = 0.0f;
        #pragma unroll
        for (int s = 0; s < SLOTS; ++s) {
            si += xpart[(t * SLOTS + s) * 2 + 0];
            sg += xpart[(t * SLOTS + s) * 2 + 1];
        }
        const int* lb = label + t * 5;
        const int x1 = lb[1], y1 = lb[2], x2 = lb[3], y2 = lb[4];
        const bool valid = !((x1 == 0) && (y1 == 0) && (x2 == 0) && (y2 == 0));
        const float area = (float)((y2 - y1) * (x2 - x1));  // * C, C==1
        const float safe_area = fmaxf(area, 1.0f);
        const float vv = valid ? 1.0f : 0.0f;
        Ls[t] = sg / safe_area * vv;   // Lssim: gradient term
        L1[t] = si / safe_area * vv;   // L1loss: intensity term
    }
    __syncthreads();
    if (t < BB) {
        const float alpha = bptr[0];
        const float beta  = cptr[0];
        float cnt = 0.0f, sls = 0.0f, slin = 0.0f;
        for (int nl = 0; nl < NLB; nl++) {
            const float a = Ls[t * NLB + nl];
            const float l = L1[t * NLB + nl];
            if (a != 0.0f || l != 0.0f) cnt += 1.0f;
            sls  += a;
            slin += l;
        }
        const float safe_cnt = fmaxf(cnt, 1.0f);
        const float ls  = (cnt > 0.0f) ? (sls  / safe_cnt) : 0.0f;
        const float lin = (cnt > 0.0f) ? (slin / safe_cnt) : 0.0f;
        const float loss_label = (1.0f - beta) * ls + beta * lin;
        const float loss_in    = Sin[t] * (1.0f / (float)HWSZ);
        const float loss_grad  = Sgr[t] * (1.0f / (float)HWSZ);
        const float loss_global = alpha * loss_in + (1.0f - alpha) * loss_grad;
        out[0      + t] = 0.0f;          // loss_ss
        out[BB     + t] = loss_global;
        out[2 * BB + t] = loss_label;
        out[3 * BB + t] = loss_in;
        out[4 * BB + t] = loss_grad;
        out[5 * BB + t] = ls;
        out[6 * BB + t] = lin;
    }
}

extern "C" void kernel_launch(void* const* d_in, const int* in_sizes, int n_in,
                              void* d_out, int out_size, void* d_ws, size_t ws_size,
                              hipStream_t stream) {
    const float* bptr  = (const float*)d_in[0];
    const float* cptr  = (const float*)d_in[1];
    const float* vis   = (const float*)d_in[2];
    // d_in[3] = image_ir (unused by the reference)
    const float* gen   = (const float*)d_in[4];
    const int*   label = (const int*)d_in[5];
    const float* th    = (const float*)d_in[6];
    float* out = (float*)d_out;

    float* gpart = (float*)d_ws;            // GBLKS*2 floats
    float* xpart = gpart + GBLKS * 2;       // XBLKS*2 floats
    // Every slot is written unconditionally by its block — no memset needed.

    kmain<<<NWG, BLK, 0, stream>>>(vis, th, gen, label, gpart, xpart);
    kfin<<<1, 256, 0, stream>>>(gpart, xpart, label, bptr, cptr, out);
}

// Round 8
// 102.401 us; speedup vs baseline: 1.0632x; 1.0509x over previous
//
#include <hip/hip_runtime.h>

// Problem constants (fixed by setup_inputs)
#define BB     4
#define HH     640
#define WW     640
#define NLB    10
#define HWSZ   (HH * WW)     // 409600
#define BLK    128           // threads per block (2 waves)
#define PRX    4             // rows per strip (both phases)

// ---- global phase decomposition: interior (mask-free) vs boundary (masked)
// interior strips: bands 1..158 x tiles 1..158 (rows/cols 4..635) -> no padding
#define NIT    158                  // interior tiles per axis
#define NISTR  (NIT * NIT)          // 24964 interior strips per batch
#define NIBPB  196                  // ceil(NISTR/BLK) interior blocks per batch
// boundary strips: bands {0,159} all tiles + tiles {0,159} bands 1..158
#define NBSTR  636                  // boundary strips per batch
#define NBBPB  5                    // ceil(NBSTR/BLK) boundary blocks per batch
#define GPBB   (NIBPB + NBBPB)      // 201 global blocks / gpart slots per batch

// ---- box phase
#define SLOTS  20                   // band slots per box; waves cover slot + w*SLOTS
#define XPBB   (NLB * SLOTS)        // 200 box blocks per batch
#define XBLKS  (BB * XPBB)          // 800 box blocks

// ---- batch-interleaved layout + XCD-contiguous swizzle
// Logical ids: batch bb owns [bb*401, (bb+1)*401); within a batch, EVEN r ->
// global block r/2 (201), ODD r -> box block r/2 (200). An XCD's contiguous
// ~200-id chunk thus holds ~100 global + ~100 box blocks of ONE batch:
//  (a) balanced work per XCD (R5's chunking put all-global on XCDs 0-3 and
//      all-box on 4-7 -> phase imbalance), and
//  (b) box blocks re-read the SAME plane lines their batch's global tiles
//      just fetched -> L2 hits instead of a second HBM fetch.
#define BPB    (GPBB + XPBB)        // 401 blocks per batch
#define NWG    (BB * BPB)           // 1604
#define NXCD   8
#define QW     (NWG / NXCD)         // 200
#define RW     (NWG % NXCD)         // 4  (bijective m204 swizzle form)

// Reduce (vin, vgr) across a 128-thread block; thread 0 stores to dst[0..1].
__device__ __forceinline__ void reduce2_write(float vin, float vgr,
                                              float* __restrict__ dst) {
    #pragma unroll
    for (int off = 32; off > 0; off >>= 1) {
        vin += __shfl_down(vin, off);
        vgr += __shfl_down(vgr, off);
    }
    __shared__ float s0[2], s1[2];
    const int lane = threadIdx.x & 63;
    const int w    = threadIdx.x >> 6;
    if (lane == 0) { s0[w] = vin; s1[w] = vgr; }
    __syncthreads();
    if (threadIdx.x == 0) {
        dst[0] = s0[0] + s0[1];
        dst[1] = s1[0] + s1[1];
    }
}

// Process a 4-wide x PRX-tall strip with top-left center (c0, r0).
// Values outside [ry1,ry2) x [cx1,cx2) read as 0 (zero padding == mask).
// Only centers inside that rectangle accumulate (fmask).
// MASK=false: caller guarantees the full 6x6 footprint is in-bounds and every
//             center is live -> no clamps, no selects (97.5% of global strips).
// All loads are aligned float4 + independent scalars: 54 INDEPENDENT VMEM ops
// per thread, one wait. Proven optimal locally: R4 (shuffle halos: serialized,
// +20us), R6 (unaligned: line splits, +9us), R7 (LDS staging: round-trip
// serialization, +8us) all regressed against this pattern.
// m-plane = w0*v + w1*t (sobel of m via linearity).
template<bool MASK>
__device__ __forceinline__ void strip4(const float* __restrict__ v,
                                       const float* __restrict__ t,
                                       const float* __restrict__ g,
                                       int c0, int r0, int ry1, int ry2,
                                       int cx1, int cx2, float w0, float w1,
                                       float& s_in, float& s_gr) {
    // A[plane][row i][col j]; col j=0 is c0-1 .. j=5 is c0+4
    float A[3][PRX + 2][6];
    const float* P[3] = { v, t, g };
    if (MASK) {
        const int c4 = min(max(c0, 0), WW - 4);   // aligned float4 base (safe)
        const int cl = max(c0 - 1, 0);
        const int cr = min(c0 + 4, WW - 1);
        bool okc[6];
        #pragma unroll
        for (int j = 0; j < 6; ++j) {
            const int cc = c0 - 1 + j;
            okc[j] = (cc >= cx1) && (cc < cx2);
        }
        #pragma unroll
        for (int i = 0; i < PRX + 2; ++i) {
            const int rr  = r0 - 1 + i;
            const bool rok = (rr >= ry1) && (rr < ry2);
            const int rb  = min(max(rr, 0), HH - 1) * WW;
            #pragma unroll
            for (int p = 0; p < 3; ++p) {
                const float4 f = *(const float4*)(P[p] + rb + c4);
                const float eL = P[p][rb + cl];
                const float eR = P[p][rb + cr];
                A[p][i][0] = (rok && okc[0]) ? eL  : 0.0f;
                A[p][i][1] = (rok && okc[1]) ? f.x : 0.0f;
                A[p][i][2] = (rok && okc[2]) ? f.y : 0.0f;
                A[p][i][3] = (rok && okc[3]) ? f.z : 0.0f;
                A[p][i][4] = (rok && okc[4]) ? f.w : 0.0f;
                A[p][i][5] = (rok && okc[5]) ? eR  : 0.0f;
            }
        }
        #pragma unroll
        for (int s = 0; s < PRX; ++s) {
            const int rc = r0 + s;                       // center row
            const bool rcin = (rc >= ry1) && (rc < ry2);
            #pragma unroll
            for (int c = 0; c < 4; ++c) {
                float gx[3], gy[3];
                #pragma unroll
                for (int p = 0; p < 3; ++p) {
                    gx[p] = (A[p][s][c + 2] - A[p][s][c])
                          + 2.0f * (A[p][s + 1][c + 2] - A[p][s + 1][c])
                          + (A[p][s + 2][c + 2] - A[p][s + 2][c]);
                    gy[p] = (A[p][s][c] + 2.0f * A[p][s][c + 1] + A[p][s][c + 2])
                          - (A[p][s + 2][c] + 2.0f * A[p][s + 2][c + 1] + A[p][s + 2][c + 2]);
                }
                const float sv  = fabsf(gx[0]) + fabsf(gy[0]);
                const float sg  = fabsf(gx[2]) + fabsf(gy[2]);
                const float gxm = w0 * gx[0] + w1 * gx[1];
                const float gym = w0 * gy[0] + w1 * gy[1];
                const float sm  = fabsf(gxm) + fabsf(gym);
                const float vc  = A[0][s + 1][c + 1];
                const float tc  = A[1][s + 1][c + 1];
                const float gc  = A[2][s + 1][c + 1];
                const float mc  = w0 * vc + w1 * tc;
                const float inb = (rcin && okc[c + 1]) ? 1.0f : 0.0f;
                s_gr += inb * fabsf(sg - fmaxf(sv, sm));
                s_in += inb * fabsf(gc - fmaxf(vc, mc));
            }
        }
    } else {
        // ---- fast path: straight loads, identical expression tree, no selects
        #pragma unroll
        for (int i = 0; i < PRX + 2; ++i) {
            const int rb = (r0 - 1 + i) * WW;
            #pragma unroll
            for (int p = 0; p < 3; ++p) {
                const float4 f = *(const float4*)(P[p] + rb + c0);
                A[p][i][0] = P[p][rb + c0 - 1];
                A[p][i][1] = f.x;
                A[p][i][2] = f.y;
                A[p][i][3] = f.z;
                A[p][i][4] = f.w;
                A[p][i][5] = P[p][rb + c0 + 4];
            }
        }
        #pragma unroll
        for (int s = 0; s < PRX; ++s) {
            #pragma unroll
            for (int c = 0; c < 4; ++c) {
                float gx[3], gy[3];
                #pragma unroll
                for (int p = 0; p < 3; ++p) {
                    gx[p] = (A[p][s][c + 2] - A[p][s][c])
                          + 2.0f * (A[p][s + 1][c + 2] - A[p][s + 1][c])
                          + (A[p][s + 2][c + 2] - A[p][s + 2][c]);
                    gy[p] = (A[p][s][c] + 2.0f * A[p][s][c + 1] + A[p][s][c + 2])
                          - (A[p][s + 2][c] + 2.0f * A[p][s + 2][c + 1] + A[p][s + 2][c + 2]);
                }
                const float sv  = fabsf(gx[0]) + fabsf(gy[0]);
                const float sg  = fabsf(gx[2]) + fabsf(gy[2]);
                const float gxm = w0 * gx[0] + w1 * gx[1];
                const float gym = w0 * gy[0] + w1 * gy[1];
                const float sm  = fabsf(gxm) + fabsf(gym);
                const float vc  = A[0][s + 1][c + 1];
                const float tc  = A[1][s + 1][c + 1];
                const float gc  = A[2][s + 1][c + 1];
                const float mc  = w0 * vc + w1 * tc;
                s_gr += fabsf(sg - fmaxf(sv, sm));
                s_in += fabsf(gc - fmaxf(vc, mc));
            }
        }
    }
}

// ---------------- Fused main kernel ----------------
// Logical id bx -> (batch bb = bx/401, r = bx%401):
//   r even -> global block r/2 (0..195 interior, 196..200 boundary)
//   r odd  -> box block r/2 (box = bb*10 + (r/2)/20, slot = (r/2)%20)
// Every block writes its 2 partial sums to a dedicated slot (no init needed).
__global__ __launch_bounds__(BLK) void kmain(const float* __restrict__ vis,
                                             const float* __restrict__ th,
                                             const float* __restrict__ gen,
                                             const int* __restrict__ label,
                                             float* __restrict__ gpart,
                                             float* __restrict__ xpart) {
    const int t = threadIdx.x;
    // XCD-contiguous logical block id (bijective m204 form, NWG%8==4)
    const unsigned xcd = blockIdx.x % NXCD;
    const unsigned idx = blockIdx.x / NXCD;
    const unsigned bx  = (xcd < RW ? xcd * (QW + 1)
                                   : RW * (QW + 1) + (xcd - RW) * QW) + idx;
    const int bb = bx / BPB;            // batch
    const int r  = bx - bb * BPB;       // within-batch id [0, 401)
    float s_in = 0.0f, s_gr = 0.0f;
    const float* v  = vis + bb * HWSZ;
    const float* tp = th  + bb * HWSZ;
    const float* g  = gen + bb * HWSZ;
    if ((r & 1) == 0) {
        const int gidx = r >> 1;        // global block [0, 201)
        if (gidx < NIBPB) {
            // ---- global interior: strips (band, xt) in 1..158 x 1..158
            const int gi = gidx * BLK + t;
            if (gi < NISTR) {
                const int xt   = 1 + gi % NIT;
                const int band = 1 + gi / NIT;
                strip4<false>(v, tp, g, 4 * xt, 4 * band, 0, HH, 0, WW,
                              0.5f, 0.5f, s_in, s_gr);
            }
        } else {
            // ---- global boundary: 636 strips on the image frame
            const int q = (gidx - NIBPB) * BLK + t;
            if (q < NBSTR) {
                int band, xt;
                if (q < 160)      { band = 0;   xt = q; }
                else if (q < 320) { band = 159; xt = q - 160; }
                else if (q < 478) { xt = 0;     band = 1 + (q - 320); }
                else              { xt = 159;   band = 1 + (q - 478); }
                strip4<true>(v, tp, g, 4 * xt, 4 * band, 0, HH, 0, WW,
                             0.5f, 0.5f, s_in, s_gr);
            }
        }
        reduce2_write(s_in, s_gr, gpart + (bb * GPBB + gidx) * 2);
    } else {
        // ---- box phase: block = (box, slot); wave w covers bands slot+w*SLOTS,
        //      stepping 2*SLOTS bands; 64-lane x 4-col (256-wide) column tiles.
        const int e    = r >> 1;        // box-block [0, 200)
        const int lbox = e / SLOTS;
        const int slot = e - lbox * SLOTS;
        const int box  = bb * NLB + lbox;
        const int w    = t >> 6;
        const int lane = t & 63;
        const int* lb  = label + box * 5;
        const int x1 = lb[1], y1 = lb[2], x2 = lb[3], y2 = lb[4];
        const int x1a = x1 & ~3;   // aligned start; cols < x1 are masked
        for (int r0 = y1 + (slot + w * SLOTS) * PRX; r0 < y2;
             r0 += 2 * SLOTS * PRX)
            for (int cb = x1a; cb < x2; cb += 64 * 4) {
                const int c0 = cb + 4 * lane;
                // lanes fully right of the box contribute exactly 0 -> skip
                if (c0 < x2)
                    strip4<true>(v, tp, g, c0, r0, y1, y2, x1, x2,
                                 0.3f, 0.7f, s_in, s_gr);
            }
        reduce2_write(s_in, s_gr, xpart + (box * SLOTS + slot) * 2);
    }
}

// ---------------- Finalize: reduce partials, compute all 7 outputs ----------
// out layout (flat, return order): loss_ss[4], loss_global[4], loss_label[4],
//                                  loss_in[4], loss_grad[4], ls[4], lin[4]
__global__ __launch_bounds__(256) void kfin(const float* __restrict__ gpart,
                                            const float* __restrict__ xpart,
                                            const int* __restrict__ label,
                                            const float* __restrict__ bptr,
                                            const float* __restrict__ cptr,
                                            float* __restrict__ out) {
    const int t = threadIdx.x;
    __shared__ float Sin[BB], Sgr[BB];
    __shared__ float Ls[BB * NLB], L1[BB * NLB];
    // global partial reduce: wave w = batch w (slots [w*GPBB, (w+1)*GPBB))
    {
        const int w = t >> 6, l = t & 63;
        float a = 0.0f, gr = 0.0f;
        for (int j = l; j < GPBB; j += 64) {
            a  += gpart[(w * GPBB + j) * 2 + 0];
            gr += gpart[(w * GPBB + j) * 2 + 1];
        }
        #pragma unroll
        for (int off = 32; off > 0; off >>= 1) {
            a  += __shfl_down(a, off);
            gr += __shfl_down(gr, off);
        }
        if (l == 0) { Sin[w] = a; Sgr[w] = gr; }
    }
    // per-box reduce over band slots + area/valid normalization
    if (t < BB * NLB) {
        float si = 0.0f, sg = 0.0f;
        #pragma unroll
        for (int s = 0; s < SLOTS; ++s) {
            si += xpart[(t * SLOTS + s) * 2 + 0];
            sg += xpart[(t * SLOTS + s) * 2 + 1];
        }
        const int* lb = label + t * 5;
        const int x1 = lb[1], y1 = lb[2], x2 = lb[3], y2 = lb[4];
        const bool valid = !((x1 == 0) && (y1 == 0) && (x2 == 0) && (y2 == 0));
        const float area = (float)((y2 - y1) * (x2 - x1));  // * C, C==1
        const float safe_area = fmaxf(area, 1.0f);
        const float vv = valid ? 1.0f : 0.0f;
        Ls[t] = sg / safe_area * vv;   // Lssim: gradient term
        L1[t] = si / safe_area * vv;   // L1loss: intensity term
    }
    __syncthreads();
    if (t < BB) {
        const float alpha = bptr[0];
        const float beta  = cptr[0];
        float cnt = 0.0f, sls = 0.0f, slin = 0.0f;
        for (int nl = 0; nl < NLB; nl++) {
            const float a = Ls[t * NLB + nl];
            const float l = L1[t * NLB + nl];
            if (a != 0.0f || l != 0.0f) cnt += 1.0f;
            sls  += a;
            slin += l;
        }
        const float safe_cnt = fmaxf(cnt, 1.0f);
        const float ls  = (cnt > 0.0f) ? (sls  / safe_cnt) : 0.0f;
        const float lin = (cnt > 0.0f) ? (slin / safe_cnt) : 0.0f;
        const float loss_label = (1.0f - beta) * ls + beta * lin;
        const float loss_in    = Sin[t] * (1.0f / (float)HWSZ);
        const float loss_grad  = Sgr[t] * (1.0f / (float)HWSZ);
        const float loss_global = alpha * loss_in + (1.0f - alpha) * loss_grad;
        out[0      + t] = 0.0f;          // loss_ss
        out[BB     + t] = loss_global;
        out[2 * BB + t] = loss_label;
        out[3 * BB + t] = loss_in;
        out[4 * BB + t] = loss_grad;
        out[5 * BB + t] = ls;
        out[6 * BB + t] = lin;
    }
}

extern "C" void kernel_launch(void* const* d_in, const int* in_sizes, int n_in,
                              void* d_out, int out_size, void* d_ws, size_t ws_size,
                              hipStream_t stream) {
    const float* bptr  = (const float*)d_in[0];
    const float* cptr  = (const float*)d_in[1];
    const float* vis   = (const float*)d_in[2];
    // d_in[3] = image_ir (unused by the reference)
    const float* gen   = (const float*)d_in[4];
    const int*   label = (const int*)d_in[5];
    const float* th    = (const float*)d_in[6];
    float* out = (float*)d_out;

    float* gpart = (float*)d_ws;                // BB*GPBB*2 = 1608 floats
    float* xpart = gpart + BB * GPBB * 2;       // XBLKS*2   = 1600 floats
    // Every slot is written unconditionally by its block — no memset needed.

    kmain<<<NWG, BLK, 0, stream>>>(vis, th, gen, label, gpart, xpart);
    kfin<<<1, 256, 0, stream>>>(gpart, xpart, label, bptr, cptr, out);
}

// Round 9
// 100.970 us; speedup vs baseline: 1.0782x; 1.0142x over previous
//
#include <hip/hip_runtime.h>

// Problem constants (fixed by setup_inputs)
#define BB     4
#define HH     640
#define WW     640
#define NLB    10
#define HWSZ   (HH * WW)     // 409600
#define BLK    128           // threads per block (2 waves)
#define PRX    4             // rows per strip (both phases)

// ---- global phase decomposition: interior (mask-free) vs boundary (masked)
// interior strips: bands 1..158 x tiles 1..158 (rows/cols 4..635) -> no padding
#define NIT    158                  // interior tiles per axis
#define NISTR  (NIT * NIT)          // 24964 interior strips per batch
#define NIBPB  196                  // ceil(NISTR/BLK) interior blocks per batch
#define NISLOT (NIBPB * BLK)        // 25088 slots per batch (124 idle guards)
#define GIBLK  (BB * NIBPB)         // 784 interior blocks
// boundary strips: bands {0,159} all tiles + tiles {0,159} bands 1..158
#define NBSTR  636                  // boundary strips per batch
#define NBBPB  5                    // ceil(NBSTR/BLK) boundary blocks per batch
#define NBSLOT (NBBPB * BLK)        // 640 slots per batch
#define GALL   (GIBLK + BB * NBBPB) // 804 global partial slots

// ---- box phase
#define SLOTS  20                   // band slots per box; waves cover slot + w*SLOTS
#define XBLKS  (BB * NLB * SLOTS)   // 800 box blocks

// ---- XCD-contiguous swizzle (bijective for NWG % 8 != 0, m204 form)
// Measured -2.6 us (R5). Side effect of this chunking: XCDs 0-3 each own ONE
// batch's global phase (4.8MB footprint ~ L2-resident), XCDs 4-7 each own one
// batch's boxes. R8 measured that interleaving phases per chunk is WORSE (+3).
#define NWG    (GALL + XBLKS)       // 1604
#define NXCD   8
#define QW     (NWG / NXCD)         // 200
#define RW     (NWG % NXCD)         // 4

// Reduce (vin, vgr) across a 128-thread block; thread 0 stores to dst[0..1].
__device__ __forceinline__ void reduce2_write(float vin, float vgr,
                                              float* __restrict__ dst) {
    #pragma unroll
    for (int off = 32; off > 0; off >>= 1) {
        vin += __shfl_down(vin, off);
        vgr += __shfl_down(vgr, off);
    }
    __shared__ float s0[2], s1[2];
    const int lane = threadIdx.x & 63;
    const int w    = threadIdx.x >> 6;
    if (lane == 0) { s0[w] = vin; s1[w] = vgr; }
    __syncthreads();
    if (threadIdx.x == 0) {
        dst[0] = s0[0] + s0[1];
        dst[1] = s1[0] + s1[1];
    }
}

// Process a 4-wide x PRX-tall strip with top-left center (c0, r0).
// Values outside [ry1,ry2) x [cx1,cx2) read as 0 (zero padding == mask).
// Only centers inside that rectangle accumulate (fmask).
// MASK=false: caller guarantees the full 6x6 footprint is in-bounds and every
//             center is live -> no clamps, no selects (97.5% of global strips).
// All loads are aligned float4 + independent scalars: 54 INDEPENDENT VMEM ops
// per thread, one wait. Locally optimal — probed alternatives all regressed:
// R4 shuffle halos (+20us, serialization), R6 unaligned loads (+9us, line
// splits), R7 LDS staging (+8us, round-trip serialization).
// m-plane = w0*v + w1*t (sobel of m via linearity).
template<bool MASK>
__device__ __forceinline__ void strip4(const float* __restrict__ v,
                                       const float* __restrict__ t,
                                       const float* __restrict__ g,
                                       int c0, int r0, int ry1, int ry2,
                                       int cx1, int cx2, float w0, float w1,
                                       float& s_in, float& s_gr) {
    // A[plane][row i][col j]; col j=0 is c0-1 .. j=5 is c0+4
    float A[3][PRX + 2][6];
    const float* P[3] = { v, t, g };
    if (MASK) {
        const int c4 = min(max(c0, 0), WW - 4);   // aligned float4 base (safe)
        const int cl = max(c0 - 1, 0);
        const int cr = min(c0 + 4, WW - 1);
        bool okc[6];
        #pragma unroll
        for (int j = 0; j < 6; ++j) {
            const int cc = c0 - 1 + j;
            okc[j] = (cc >= cx1) && (cc < cx2);
        }
        #pragma unroll
        for (int i = 0; i < PRX + 2; ++i) {
            const int rr  = r0 - 1 + i;
            const bool rok = (rr >= ry1) && (rr < ry2);
            const int rb  = min(max(rr, 0), HH - 1) * WW;
            #pragma unroll
            for (int p = 0; p < 3; ++p) {
                const float4 f = *(const float4*)(P[p] + rb + c4);
                const float eL = P[p][rb + cl];
                const float eR = P[p][rb + cr];
                A[p][i][0] = (rok && okc[0]) ? eL  : 0.0f;
                A[p][i][1] = (rok && okc[1]) ? f.x : 0.0f;
                A[p][i][2] = (rok && okc[2]) ? f.y : 0.0f;
                A[p][i][3] = (rok && okc[3]) ? f.z : 0.0f;
                A[p][i][4] = (rok && okc[4]) ? f.w : 0.0f;
                A[p][i][5] = (rok && okc[5]) ? eR  : 0.0f;
            }
        }
        #pragma unroll
        for (int s = 0; s < PRX; ++s) {
            const int rc = r0 + s;                       // center row
            const bool rcin = (rc >= ry1) && (rc < ry2);
            #pragma unroll
            for (int c = 0; c < 4; ++c) {
                float gx[3], gy[3];
                #pragma unroll
                for (int p = 0; p < 3; ++p) {
                    gx[p] = (A[p][s][c + 2] - A[p][s][c])
                          + 2.0f * (A[p][s + 1][c + 2] - A[p][s + 1][c])
                          + (A[p][s + 2][c + 2] - A[p][s + 2][c]);
                    gy[p] = (A[p][s][c] + 2.0f * A[p][s][c + 1] + A[p][s][c + 2])
                          - (A[p][s + 2][c] + 2.0f * A[p][s + 2][c + 1] + A[p][s + 2][c + 2]);
                }
                const float sv  = fabsf(gx[0]) + fabsf(gy[0]);
                const float sg  = fabsf(gx[2]) + fabsf(gy[2]);
                const float gxm = w0 * gx[0] + w1 * gx[1];
                const float gym = w0 * gy[0] + w1 * gy[1];
                const float sm  = fabsf(gxm) + fabsf(gym);
                const float vc  = A[0][s + 1][c + 1];
                const float tc  = A[1][s + 1][c + 1];
                const float gc  = A[2][s + 1][c + 1];
                const float mc  = w0 * vc + w1 * tc;
                const float inb = (rcin && okc[c + 1]) ? 1.0f : 0.0f;
                s_gr += inb * fabsf(sg - fmaxf(sv, sm));
                s_in += inb * fabsf(gc - fmaxf(vc, mc));
            }
        }
    } else {
        // ---- fast path: straight loads, identical expression tree, no selects
        #pragma unroll
        for (int i = 0; i < PRX + 2; ++i) {
            const int rb = (r0 - 1 + i) * WW;
            #pragma unroll
            for (int p = 0; p < 3; ++p) {
                const float4 f = *(const float4*)(P[p] + rb + c0);
                A[p][i][0] = P[p][rb + c0 - 1];
                A[p][i][1] = f.x;
                A[p][i][2] = f.y;
                A[p][i][3] = f.z;
                A[p][i][4] = f.w;
                A[p][i][5] = P[p][rb + c0 + 4];
            }
        }
        #pragma unroll
        for (int s = 0; s < PRX; ++s) {
            #pragma unroll
            for (int c = 0; c < 4; ++c) {
                float gx[3], gy[3];
                #pragma unroll
                for (int p = 0; p < 3; ++p) {
                    gx[p] = (A[p][s][c + 2] - A[p][s][c])
                          + 2.0f * (A[p][s + 1][c + 2] - A[p][s + 1][c])
                          + (A[p][s + 2][c + 2] - A[p][s + 2][c]);
                    gy[p] = (A[p][s][c] + 2.0f * A[p][s][c + 1] + A[p][s][c + 2])
                          - (A[p][s + 2][c] + 2.0f * A[p][s + 2][c + 1] + A[p][s + 2][c + 2]);
                }
                const float sv  = fabsf(gx[0]) + fabsf(gy[0]);
                const float sg  = fabsf(gx[2]) + fabsf(gy[2]);
                const float gxm = w0 * gx[0] + w1 * gx[1];
                const float gym = w0 * gy[0] + w1 * gy[1];
                const float sm  = fabsf(gxm) + fabsf(gym);
                const float vc  = A[0][s + 1][c + 1];
                const float tc  = A[1][s + 1][c + 1];
                const float gc  = A[2][s + 1][c + 1];
                const float mc  = w0 * vc + w1 * tc;
                s_gr += fabsf(sg - fmaxf(sv, sm));
                s_in += fabsf(gc - fmaxf(vc, mc));
            }
        }
    }
}

// ---------------- Fused main kernel ----------------
// logical blocks [0, GIBLK):          global interior strips (fast path)
// logical blocks [GIBLK, GALL):       global boundary strips (masked path)
// logical blocks [GALL, GALL+XBLKS):  box bands (masked path)
// Every block writes its 2 partial sums to a dedicated slot (no init needed).
__global__ __launch_bounds__(BLK) void kmain(const float* __restrict__ vis,
                                             const float* __restrict__ th,
                                             const float* __restrict__ gen,
                                             const int* __restrict__ label,
                                             float* __restrict__ gpart,
                                             float* __restrict__ xpart) {
    const int t = threadIdx.x;
    // XCD-contiguous logical block id (bijective; see #define block comment)
    const unsigned xcd = blockIdx.x % NXCD;
    const unsigned idx = blockIdx.x / NXCD;
    const unsigned bx  = (xcd < RW ? xcd * (QW + 1)
                                   : RW * (QW + 1) + (xcd - RW) * QW) + idx;
    float s_in = 0.0f, s_gr = 0.0f;
    if (bx < GIBLK) {
        // ---- global interior: gi -> (batch, band, xt), bands/tiles 1..158
        const int gi = bx * BLK + t;
        const int b  = gi / NISLOT;
        const int r  = gi - b * NISLOT;
        if (r < NISTR) {
            const int xt   = 1 + r % NIT;
            const int band = 1 + r / NIT;
            strip4<false>(vis + b * HWSZ, th + b * HWSZ, gen + b * HWSZ,
                          4 * xt, 4 * band, 0, HH, 0, WW, 0.5f, 0.5f,
                          s_in, s_gr);
        }
        reduce2_write(s_in, s_gr, gpart + bx * 2);
    } else if (bx < GALL) {
        // ---- global boundary: 636 strips/batch on the image frame
        const int q = (bx - GIBLK) * BLK + t;
        const int b = q / NBSLOT;
        const int r = q - b * NBSLOT;
        if (r < NBSTR) {
            int band, xt;
            if (r < 160)      { band = 0;   xt = r; }
            else if (r < 320) { band = 159; xt = r - 160; }
            else if (r < 478) { xt = 0;     band = 1 + (r - 320); }
            else              { xt = 159;   band = 1 + (r - 478); }
            strip4<true>(vis + b * HWSZ, th + b * HWSZ, gen + b * HWSZ,
                         4 * xt, 4 * band, 0, HH, 0, WW, 0.5f, 0.5f,
                         s_in, s_gr);
        }
        reduce2_write(s_in, s_gr, gpart + bx * 2);
    } else {
        // ---- box phase: block = (box, slot); wave w covers bands slot+w*SLOTS,
        //      stepping 2*SLOTS bands; 64-lane x 4-col (256-wide) column tiles.
        const int q    = bx - GALL;
        const int box  = q / SLOTS;
        const int slot = q % SLOTS;
        const int b    = box / NLB;
        const int w    = t >> 6;
        const int lane = t & 63;
        const int* lb  = label + box * 5;
        const int x1 = lb[1], y1 = lb[2], x2 = lb[3], y2 = lb[4];
        const int x1a = x1 & ~3;   // aligned start; cols < x1 are masked
        const float* v  = vis + b * HWSZ;
        const float* tp = th  + b * HWSZ;
        const float* g  = gen + b * HWSZ;
        for (int r0 = y1 + (slot + w * SLOTS) * PRX; r0 < y2;
             r0 += 2 * SLOTS * PRX)
            for (int cb = x1a; cb < x2; cb += 64 * 4) {
                const int c0 = cb + 4 * lane;
                // lanes fully right of the box contribute exactly 0 -> skip
                if (c0 < x2)
                    strip4<true>(v, tp, g, c0, r0, y1, y2, x1, x2,
                                 0.3f, 0.7f, s_in, s_gr);
            }
        reduce2_write(s_in, s_gr, xpart + q * 2);
    }
}

// ---------------- Finalize: reduce partials, compute all 7 outputs ----------
// out layout (flat, return order): loss_ss[4], loss_global[4], loss_label[4],
//                                  loss_in[4], loss_grad[4], ls[4], lin[4]
__global__ __launch_bounds__(256) void kfin(const float* __restrict__ gpart,
                                            const float* __restrict__ xpart,
                                            const int* __restrict__ label,
                                            const float* __restrict__ bptr,
                                            const float* __restrict__ cptr,
                                            float* __restrict__ out) {
    const int t = threadIdx.x;
    __shared__ float Sin[BB], Sgr[BB];
    __shared__ float Ls[BB * NLB], L1[BB * NLB];
    // global partial reduce: wave w = batch w
    //   interior blocks [w*NIBPB, (w+1)*NIBPB) + boundary [GIBLK+w*NBBPB, +NBBPB)
    {
        const int w = t >> 6, l = t & 63;
        float a = 0.0f, gr = 0.0f;
        for (int j = l; j < NIBPB; j += 64) {
            a  += gpart[(w * NIBPB + j) * 2 + 0];
            gr += gpart[(w * NIBPB + j) * 2 + 1];
        }
        if (l < NBBPB) {
            const int idx = GIBLK + w * NBBPB + l;
            a  += gpart[idx * 2 + 0];
            gr += gpart[idx * 2 + 1];
        }
        #pragma unroll
        for (int off = 32; off > 0; off >>= 1) {
            a  += __shfl_down(a, off);
            gr += __shfl_down(gr, off);
        }
        if (l == 0) { Sin[w] = a; Sgr[w] = gr; }
    }
    // per-box reduce over band slots + area/valid normalization
    if (t < BB * NLB) {
        float si = 0.0f, sg = 0.0f;
        #pragma unroll
        for (int s = 0; s < SLOTS; ++s) {
            si += xpart[(t * SLOTS + s) * 2 + 0];
            sg += xpart[(t * SLOTS + s) * 2 + 1];
        }
        const int* lb = label + t * 5;
        const int x1 = lb[1], y1 = lb[2], x2 = lb[3], y2 = lb[4];
        const bool valid = !((x1 == 0) && (y1 == 0) && (x2 == 0) && (y2 == 0));
        const float area = (float)((y2 - y1) * (x2 - x1));  // * C, C==1
        const float safe_area = fmaxf(area, 1.0f);
        const float vv = valid ? 1.0f : 0.0f;
        Ls[t] = sg / safe_area * vv;   // Lssim: gradient term
        L1[t] = si / safe_area * vv;   // L1loss: intensity term
    }
    __syncthreads();
    if (t < BB) {
        const float alpha = bptr[0];
        const float beta  = cptr[0];
        float cnt = 0.0f, sls = 0.0f, slin = 0.0f;
        for (int nl = 0; nl < NLB; nl++) {
            const float a = Ls[t * NLB + nl];
            const float l = L1[t * NLB + nl];
            if (a != 0.0f || l != 0.0f) cnt += 1.0f;
            sls  += a;
            slin += l;
        }
        const float safe_cnt = fmaxf(cnt, 1.0f);
        const float ls  = (cnt > 0.0f) ? (sls  / safe_cnt) : 0.0f;
        const float lin = (cnt > 0.0f) ? (slin / safe_cnt) : 0.0f;
        const float loss_label = (1.0f - beta) * ls + beta * lin;
        const float loss_in    = Sin[t] * (1.0f / (float)HWSZ);
        const float loss_grad  = Sgr[t] * (1.0f / (float)HWSZ);
        const float loss_global = alpha * loss_in + (1.0f - alpha) * loss_grad;
        out[0      + t] = 0.0f;          // loss_ss
        out[BB     + t] = loss_global;
        out[2 * BB + t] = loss_label;
        out[3 * BB + t] = loss_in;
        out[4 * BB + t] = loss_grad;
        out[5 * BB + t] = ls;
        out[6 * BB + t] = lin;
    }
}

extern "C" void kernel_launch(void* const* d_in, const int* in_sizes, int n_in,
                              void* d_out, int out_size, void* d_ws, size_t ws_size,
                              hipStream_t stream) {
    const float* bptr  = (const float*)d_in[0];
    const float* cptr  = (const float*)d_in[1];
    const float* vis   = (const float*)d_in[2];
    // d_in[3] = image_ir (unused by the reference)
    const float* gen   = (const float*)d_in[4];
    const int*   label = (const int*)d_in[5];
    const float* th    = (const float*)d_in[6];
    float* out = (float*)d_out;

    float* gpart = (float*)d_ws;            // GALL*2 floats
    float* xpart = gpart + GALL * 2;        // XBLKS*2 floats
    // Every slot is written unconditionally by its block — no memset needed.

    kmain<<<NWG, BLK, 0, stream>>>(vis, th, gen, label, gpart, xpart);
    kfin<<<1, 256, 0, stream>>>(gpart, xpart, label, bptr, cptr, out);
}